// Round 4
// 147.512 us; speedup vs baseline: 1.0400x; 1.0400x over previous
//
#include <hip/hip_runtime.h>

#define HH 768
#define NN 64
#define LL 2048
#define BB 4

typedef __attribute__((ext_vector_type(2))) float f32x2;
typedef __attribute__((ext_vector_type(4))) float f32x4;
typedef __attribute__((ext_vector_type(8))) short bf16x8;
typedef __attribute__((ext_vector_type(4))) short bf16x4;

// ---- LDS pool (all regions 16B aligned) ----
#define UF_OFF   0        // u fp32: 32 rows x 68 floats             = 8704 B
#define WRH_OFF  8704     // W real hi-bf16: 64 rows x 68 shorts     = 8704 B
#define WRL_OFF  17408    // W real lo-bf16: 64 rows x 68 shorts     = 8704 B
#define WIT_OFF  26112    // W imag bf16 (RNE): 64 rows x 68 shorts  = 8704 B
#define SZ_OFF   34816    // 32 slots x 544 B: S fp32 -> X bf16-split= 17408 B
#define KP_OFF   52224    // kpad: 128 floats ([0..63]=0,[64+t]=K[t])= 512 B
#define AB_OFF   52736    // Abar 64 float2                          = 512 B
#define CB_OFF   53248    // CBb  64 float2                          = 512 B
#define POOL_SZ  53760    // 52.5 KB -> 3 blocks/CU

__device__ __forceinline__ float2 cmul(float2 a, float2 b) {
    return make_float2(fmaf(a.x, b.x, -(a.y * b.y)), fmaf(a.x, b.y, a.y * b.x));
}
__device__ __forceinline__ unsigned short f2bf(float x) {   // RNE float->bf16
    union { float f; unsigned u; } v; v.f = x;
    return (unsigned short)((v.u + 0x7fffu + ((v.u >> 16) & 1u)) >> 16);
}
__device__ __forceinline__ unsigned fbits(float x) { union { float f; unsigned u; } v; v.f = x; return v.u; }
__device__ __forceinline__ float bitsf(unsigned u) { union { unsigned u; float f; } v; v.u = u; return v.f; }
// RNE two-level split: x ~= h + l, both RNE bf16. h within half-ulp of x,
// r = x - h exact (Sterbenz), l within half-ulp of r => |x-(h+l)| <~ 2^-19|x|,
// zero systematic bias (vs truncation: coherent -2^-16|x| bias -> 0.05 absmax).
__device__ __forceinline__ void tsplit(float x, short& h, short& l) {
    const unsigned bx = fbits(x);
    const unsigned hu = (bx + 0x7fffu + ((bx >> 16) & 1u)) >> 16;
    h = (short)hu;
    const float r = x - bitsf(hu << 16);
    const unsigned br = fbits(r);
    l = (short)((br + 0x7fffu + ((br >> 16) & 1u)) >> 16);
}
// packed fp32 helpers (encode path, unchanged)
__device__ __forceinline__ f32x2 pkfma(f32x2 a, f32x2 b, f32x2 c) {
    return __builtin_elementwise_fma(a, b, c);
}
__device__ __forceinline__ f32x2 splat2(float x) { return (f32x2){x, x}; }
__device__ __forceinline__ f32x2 swapneg(f32x2 v) { return (f32x2){-v[1], v[0]}; }
__device__ __forceinline__ f32x2 cmul2(f32x2 a, f32x2 b) {
    return pkfma(splat2(a[0]), b, splat2(a[1]) * swapneg(b));
}
__device__ __forceinline__ f32x4 mm_bf16(bf16x8 a, bf16x8 b, f32x4 c) {
    return __builtin_amdgcn_mfma_f32_16x16x32_bf16(a, b, c, 0, 0, 0);
}
__device__ __forceinline__ bf16x8 ldw8(const short* p) {   // 2 x b64 (rows only 8B aligned)
    const bf16x4 a = *(const bf16x4*)p;
    const bf16x4 b = *(const bf16x4*)(p + 4);
    return __builtin_shufflevector(a, b, 0, 1, 2, 3, 4, 5, 6, 7);
}
__device__ __forceinline__ void split8(const float* p, bf16x8& h8, bf16x8& l8) {
    const float4 a = *(const float4*)p;
    const float4 b = *(const float4*)(p + 4);
    short h, l;
    tsplit(a.x, h, l); h8[0] = h; l8[0] = l;
    tsplit(a.y, h, l); h8[1] = h; l8[1] = l;
    tsplit(a.z, h, l); h8[2] = h; l8[2] = l;
    tsplit(a.w, h, l); h8[3] = h; l8[3] = l;
    tsplit(b.x, h, l); h8[4] = h; l8[4] = l;
    tsplit(b.y, h, l); h8[5] = h; l8[5] = l;
    tsplit(b.z, h, l); h8[6] = h; l8[6] = l;
    tsplit(b.w, h, l); h8[7] = h; l8[7] = l;
}

__global__ __launch_bounds__(256, 3) void ssm_kernel10(
    const float* __restrict__ ug,
    const float* __restrict__ lnr,
    const float* __restrict__ img,
    const float* __restrict__ Brp,
    const float* __restrict__ Bip,
    const float* __restrict__ Crp,
    const float* __restrict__ Cip,
    const float* __restrict__ ldt,
    const float* __restrict__ Dp,
    float* __restrict__ outg)
{
    __shared__ __align__(16) unsigned char POOL[POOL_SZ];
    float*  UF   = (float*)(POOL + UF_OFF);
    short*  WRH  = (short*)(POOL + WRH_OFF);
    short*  WRL  = (short*)(POOL + WRL_OFF);
    short*  WIT  = (short*)(POOL + WIT_OFF);
    float*  kpad = (float*)(POOL + KP_OFF);
    float2* Abar = (float2*)(POOL + AB_OFF);
    float2* CBb  = (float2*)(POOL + CB_OFF);

    const int tid = threadIdx.x;
    const int h = blockIdx.x % HH;
    const int b = blockIdx.x / HH;
    const int lane = tid & 63;
    const int w = tid >> 6;

    const float dt = expf(ldt[h]);
    const float Dh = Dp[h];

    // ---- P0: per-state params + kpad zero pad + K[0] (wave0 butterfly) ----
    if (tid < NN) {
        const int n = tid;
        const float lre = -expf(lnr[h * NN + n]);
        const float lim = img[h * NN + n];
        const float e = expf(lre * dt);
        const float th = lim * dt;
        const float2 A = make_float2(e * cosf(th), e * sinf(th));
        const float den = lre * lre + lim * lim;
        const float2 invL = make_float2(lre / den, -lim / den);
        const float2 am1 = make_float2(A.x - 1.0f, A.y);
        const float2 Bb = cmul(cmul(am1, invL), make_float2(Brp[h*NN+n], Bip[h*NN+n]));
        const float2 CB = cmul(make_float2(Crp[h*NN+n], Cip[h*NN+n]), Bb);
        Abar[n] = A;
        CBb[n] = CB;
        kpad[n] = 0.f;
        // K[0] = sum_n Re(CB)
        float r = CB.x;
        r += __shfl_xor(r, 1);  r += __shfl_xor(r, 2);  r += __shfl_xor(r, 4);
        r += __shfl_xor(r, 8);  r += __shfl_xor(r, 16); r += __shfl_xor(r, 32);
        if (n == 0) kpad[64] = r;
    }
    // ---- P0b: stage u fp32 chunk-padded (stride 68) ----
    {
        const float4* u4g = (const float4*)(ug + (size_t)(b * HH + h) * LL);
        float4* uf4 = (float4*)UF;
        #pragma unroll
        for (int r = 0; r < 2; ++r) {
            const int i = tid + 256 * r;
            uf4[(i >> 4) * 17 + (i & 15)] = u4g[i];
        }
    }
    __syncthreads();   // b0

    // ---- P1: W tables, transposed + bf16-split. W[n][j] = CB_n*A_n^(j+1).
    //      WRH/WRL[j*68+n] = hi/lo(Re) RNE, WIT[j*68+n] = RNE bf16(Im).
    //      Also K[j+1] = sum_n Re(W[n][j]) via fp32 butterfly. ----
    {
        const float2 A = Abar[lane];
        const float2 a2 = cmul(A, A), a4 = cmul(a2, a2), a8 = cmul(a4, a4), a16 = cmul(a8, a8);
        float2 pw = cmul(CBb[lane], A);
        for (int i = 0; i < w; ++i) pw = cmul(pw, a16);
        #pragma unroll
        for (int jj = 0; jj < 16; ++jj) {
            const int j = 16 * w + jj;
            short hre, lre2;
            tsplit(pw.x, hre, lre2);
            WRH[j * 68 + lane] = hre;
            WRL[j * 68 + lane] = lre2;
            WIT[j * 68 + lane] = (short)f2bf(pw.y);
            float r = pw.x;
            r += __shfl_xor(r, 1);  r += __shfl_xor(r, 2);  r += __shfl_xor(r, 4);
            r += __shfl_xor(r, 8);  r += __shfl_xor(r, 16); r += __shfl_xor(r, 32);
            if (lane == 0 && j < 63) kpad[65 + j] = r;
            pw = cmul(pw, A);
        }
    }
    __syncthreads();   // b1: W tables + full kpad ready

    // ---- P2b: packed 4-step-fused Horner encode (unchanged, r6-proven) ----
    f32x2 Sres[8];
    {
        const float2 Af = Abar[lane];
        const f32x2 A1 = {Af.x, Af.y};
        const f32x2 A2 = cmul2(A1, A1);
        const f32x2 A3 = cmul2(A2, A1);
        const f32x2 A4 = cmul2(A2, A2);
        const f32x2 A8 = cmul2(A4, A4);
        f32x2 P8[8];
        P8[0] = (f32x2){1.f, 0.f};
        #pragma unroll
        for (int k = 1; k < 8; ++k) P8[k] = cmul2(P8[k-1], A8);
        const float4* uf4 = (const float4*)UF;
        #pragma unroll
        for (int k8 = 0; k8 < 8; ++k8) {
            const int c = w + 4 * k8;
            f32x2 sg[8];
            #pragma unroll
            for (int g = 0; g < 8; ++g) {
                const float4 ua = uf4[c * 17 + 2 * g];
                const float4 ub = uf4[c * 17 + 2 * g + 1];
                f32x2 t = A3 * ua.x;
                t = pkfma(A2, splat2(ua.y), t);
                t = pkfma(A1, splat2(ua.z), t);
                t[0] += ua.w;
                f32x2 t2 = A3 * ub.x;
                t2 = pkfma(A2, splat2(ub.y), t2);
                t2 = pkfma(A1, splat2(ub.z), t2);
                t2[0] += ub.w;
                sg[g] = pkfma(splat2(A4[0]), t, pkfma(splat2(A4[1]), swapneg(t), t2));
            }
            f32x2 S = sg[7];
            #pragma unroll
            for (int g = 0; g < 7; ++g)
                S = pkfma(splat2(P8[7-g][0]), sg[g], pkfma(splat2(P8[7-g][1]), swapneg(sg[g]), S));
            Sres[k8] = S;
        }
    }
    // ---- P3: write S fp32 into slots (re at [0:64), im at [64:128) floats) ----
    #pragma unroll
    for (int k8 = 0; k8 < 8; ++k8) {
        const int c = w + 4 * k8;
        float* Sf = (float*)(POOL + SZ_OFF + c * 544);
        Sf[lane]      = Sres[k8][0];
        Sf[64 + lane] = Sres[k8][1];
    }
    __syncthreads();   // b2: S ready

    // ---- P4a: scan (wave 0), fp32 state; emits X[c] (pre-state) as bf16-split
    //      in place: XRH@+0, XRL@+128B, XIH(-xi)@+256B, XIL@+384B (shorts).
    //      The short writes alias OTHER lanes' float reads within the wave ->
    //      drain ds_reads (lgkmcnt) before issuing the writes. ----
    if (w == 0) {
        const float2 A = Abar[lane];
        const float2 a2 = cmul(A, A), a4 = cmul(a2, a2), a8 = cmul(a4, a4),
                     a16 = cmul(a8, a8), a32 = cmul(a16, a16), a64 = cmul(a32, a32);
        float xr = 0.f, xi = 0.f;
        unsigned char* szb = POOL + SZ_OFF;
        for (int c = 0; c < 32; ++c) {
            float* Sf = (float*)(szb + c * 544);
            const float sr = Sf[lane];
            const float si = Sf[64 + lane];
            // force HW completion of the reads before issuing aliasing writes
            asm volatile("s_waitcnt lgkmcnt(0)" ::: "memory");
            short* XS = (short*)(szb + c * 544);
            short hh, ll;
            tsplit(xr, hh, ll);
            XS[lane]       = hh;
            XS[64 + lane]  = ll;
            const float nxi = -xi;
            tsplit(nxi, hh, ll);
            XS[128 + lane] = hh;
            XS[192 + lane] = ll;
            const float nxr = fmaf(a64.x, xr, fmaf(-a64.y, xi, sr));
            xi = fmaf(a64.x, xi, fmaf(a64.y, xr, si));
            xr = nxr;
        }
    }

    // ---- P4b: intra-chunk causal conv via MFMA.
    //      Y[c][j] += sum_s U[c][s] * K[j-s]; A-frag k-axis and B-frag k-axis
    //      generated with the SAME (group,elem)->s formula so any internal
    //      k-permutation cancels. kpad's zero pad realizes the triangle. ----
    const int g4 = lane >> 4;
    const int jq = lane & 15;
    const int jcol = 16 * w + jq;
    f32x4 acc0 = {0.f, 0.f, 0.f, 0.f};
    f32x4 acc1 = {0.f, 0.f, 0.f, 0.f};
    {
        auto cstep = [&](int ks) {
            bf16x8 mh, ml;
            const int kbase = 64 + jcol - 32 * ks - 8 * g4;
            #pragma unroll
            for (int i = 0; i < 8; ++i) {
                short hh, ll; tsplit(kpad[kbase - i], hh, ll);
                mh[i] = hh; ml[i] = ll;
            }
            bf16x8 uh, ul;
            split8(UF + jq * 68 + 32 * ks + 8 * g4, uh, ul);
            acc0 = mm_bf16(uh, mh, acc0); acc0 = mm_bf16(uh, ml, acc0); acc0 = mm_bf16(ul, mh, acc0);
            split8(UF + (16 + jq) * 68 + 32 * ks + 8 * g4, uh, ul);
            acc1 = mm_bf16(uh, mh, acc1); acc1 = mm_bf16(uh, ml, acc1); acc1 = mm_bf16(ul, mh, acc1);
        };
        cstep(0);
        if (w >= 2) cstep(1);   // s in [32,64) only reaches j >= 32
    }
    // ---- W-fragment preload (tables ready since b1) ----
    const short* wrhp = WRH + jcol * 68 + 8 * g4;
    const short* wrlp = WRL + jcol * 68 + 8 * g4;
    const short* witp = WIT + jcol * 68 + 8 * g4;
    const bf16x8 wrh0 = ldw8(wrhp), wrh1 = ldw8(wrhp + 32);
    const bf16x8 wrl0 = ldw8(wrlp), wrl1 = ldw8(wrlp + 32);
    const bf16x8 wim0 = ldw8(witp), wim1 = ldw8(witp + 32);
    __syncthreads();   // b3: X ready

    // ---- P5: boundary via MFMA: Y[c][j] += xr*WreHi + xr*WreLo + xrLo*WreHi
    //                                   + (-xi)hi*Wim + (-xi)lo*Wim ----
    {
        const short* xq = (const short*)(POOL + SZ_OFF) + jq * 272 + 8 * g4;
        auto bnd = [&](const short* xp, f32x4 acc) -> f32x4 {
            bf16x8 t;
            t = *(const bf16x8*)(xp);        acc = mm_bf16(t, wrh0, acc); acc = mm_bf16(t, wrl0, acc);
            t = *(const bf16x8*)(xp + 64);   acc = mm_bf16(t, wrh0, acc);
            t = *(const bf16x8*)(xp + 128);  acc = mm_bf16(t, wim0, acc);
            t = *(const bf16x8*)(xp + 192);  acc = mm_bf16(t, wim0, acc);
            t = *(const bf16x8*)(xp + 32);   acc = mm_bf16(t, wrh1, acc); acc = mm_bf16(t, wrl1, acc);
            t = *(const bf16x8*)(xp + 96);   acc = mm_bf16(t, wrh1, acc);
            t = *(const bf16x8*)(xp + 160);  acc = mm_bf16(t, wim1, acc);
            t = *(const bf16x8*)(xp + 224);  acc = mm_bf16(t, wim1, acc);
            return acc;
        };
        acc0 = bnd(xq, acc0);
        acc1 = bnd(xq + 16 * 272, acc1);
    }

    // ---- Epilogue: y = acc + D*u; C/D layout col=lane&15, row=4*(lane>>4)+reg ----
    {
        float* og = outg + (size_t)(b * HH + h) * LL;
        #pragma unroll
        for (int r = 0; r < 4; ++r) {
            const int ca = 4 * g4 + r;
            const int cb = ca + 16;
            og[ca * 64 + jcol] = fmaf(Dh, UF[ca * 68 + jcol], acc0[r]);
            og[cb * 64 + jcol] = fmaf(Dh, UF[cb * 68 + jcol], acc1[r]);
        }
    }
}

extern "C" void kernel_launch(void* const* d_in, const int* in_sizes, int n_in,
                              void* d_out, int out_size, void* d_ws, size_t ws_size,
                              hipStream_t stream) {
    (void)in_sizes; (void)n_in; (void)out_size; (void)d_ws; (void)ws_size;
    ssm_kernel10<<<dim3(BB * HH), dim3(256), 0, stream>>>(
        (const float*)d_in[0], (const float*)d_in[1], (const float*)d_in[2],
        (const float*)d_in[3], (const float*)d_in[4], (const float*)d_in[5],
        (const float*)d_in[6], (const float*)d_in[7], (const float*)d_in[8],
        (float*)d_out);
}